// Round 10
// baseline (263.652 us; speedup 1.0000x reference)
//
#include <hip/hip_runtime.h>
#include <hip/hip_bf16.h>
#include <hip/hip_cooperative_groups.h>

namespace cg = cooperative_groups;

#define NN 512
#define BB 256

typedef unsigned short u16;
typedef unsigned int u32;
typedef __attribute__((ext_vector_type(8))) short bf16x8;
typedef __attribute__((ext_vector_type(4))) short u16x4;
typedef __attribute__((ext_vector_type(4))) float f32x4;
typedef __attribute__((ext_vector_type(4))) u32 u32x4;

__device__ __forceinline__ u16 f2bf(float x){
  u32 u = __builtin_bit_cast(u32, x);
  u32 r = u + 0x7fffu + ((u >> 16) & 1u);
  return (u16)(r >> 16);
}
__device__ __forceinline__ float bf2f(u16 h){
  return __builtin_bit_cast(float, (u32)h << 16);
}
__device__ __forceinline__ u32 cvtpk(float lo, float hi){
  float2 t; t.x = lo; t.y = hi;
  __hip_bfloat162 h = __float22bfloat162_rn(t);
  u32 r;
  __builtin_memcpy(&r, &h, 4);
  return r;
}
__device__ __forceinline__ bf16x8 pack8nc(float4 u, float4 v){
  u32x4 w;
  w[0] = cvtpk(u.x, u.y);
  w[1] = cvtpk(u.z, u.w);
  w[2] = cvtpk(v.x, v.y);
  w[3] = cvtpk(v.z, v.w);
  return __builtin_bit_cast(bf16x8, w);
}

// ---------------- K0: cast features f32->bf16  +  WaT build (fused) ----------------
__global__ __launch_bounds__(256) void k_prep(const float* __restrict__ f, u16* __restrict__ fb,
                                              const float* __restrict__ Wa, u16* __restrict__ wat){
  int b = blockIdx.x;
  if (b < 4096){
    int i = b * 256 + threadIdx.x;                  // 8 bf16 per thread
    const float4* p = (const float4*)f;
    float4 a = p[2*i], c = p[2*i+1];
    uint4 o;
    o.x = cvtpk(a.x, a.y); o.y = cvtpk(a.z, a.w);
    o.z = cvtpk(c.x, c.y); o.w = cvtpk(c.z, c.w);
    ((uint4*)fb)[i] = o;
  } else {
    int t = (b - 4096) * 256 + threadIdx.x;         // 64*192 = 12288 exact (48 blocks)
    int o = t / 192, r = t - o * 192;
    int blk = r >> 6, q = r & 63;
    float v = 0.f;
    if (blk == 0) v = Wa[q * 64 + o];
    else if (blk == 1) { if (q < 32) v = Wa[(64 + q) * 64 + o]; }
    else v = Wa[(96 + q) * 64 + o];
    wat[t] = f2bf(v);
  }
}

// ---------------- fold one hop's W' into a 8KB swizzled LDS slot ----------------
__device__ __forceinline__ void fold_one(int n, int jj, char* wlj, const u16* __restrict__ wat,
    const float* __restrict__ WS, const float* __restrict__ WL3, const float* __restrict__ WL4,
    int l15, int lg)
{
  const float* src; int jb, cstride;
  if (jj < 5)      { src = WS  + ((size_t)n * 5 + jj)       * 4096; jb = 0; cstride = 64; }
  else if (jj < 7) { src = WL3 + ((size_t)n * 2 + (jj - 5)) * 2048; jb = 1; cstride = 32; }
  else             { src = WL4 + ((size_t)n * 2 + (jj - 7)) * 4096; jb = 2; cstride = 64; }

  bf16x8 bw[4][2];
  #pragma unroll
  for (int ni = 0; ni < 4; ++ni){
    int c = ni * 16 + l15;
    const float* p = src + c * cstride + lg * 8;
    float4 u = *(const float4*)p, v = *(const float4*)(p + 4);
    bw[ni][0] = pack8nc(u, v);
    if (jb != 1){
      float4 u1 = *(const float4*)(p + 32), v1 = *(const float4*)(p + 36);
      bw[ni][1] = pack8nc(u1, v1);
    }
  }
  #pragma unroll
  for (int h = 0; h < 2; ++h){
    f32x4 fa[2][4];
    #pragma unroll
    for (int mi = 0; mi < 2; ++mi)
      #pragma unroll
      for (int ni = 0; ni < 4; ++ni){ fa[mi][ni][0]=0.f; fa[mi][ni][1]=0.f; fa[mi][ni][2]=0.f; fa[mi][ni][3]=0.f; }
    #pragma unroll
    for (int ks = 0; ks < 2; ++ks){
      if (jb == 1 && ks == 1) continue;             // upper mid-block zero for L3
      bf16x8 af0 = *(const bf16x8*)(wat + (h * 32 + l15) * 192      + jb * 64 + ks * 32 + lg * 8);
      bf16x8 af1 = *(const bf16x8*)(wat + (h * 32 + 16 + l15) * 192 + jb * 64 + ks * 32 + lg * 8);
      #pragma unroll
      for (int ni = 0; ni < 4; ++ni){
        fa[0][ni] = __builtin_amdgcn_mfma_f32_16x16x32_bf16(af0, bw[ni][ks], fa[0][ni], 0, 0, 0);
        fa[1][ni] = __builtin_amdgcn_mfma_f32_16x16x32_bf16(af1, bw[ni][ks], fa[1][ni], 0, 0, 0);
      }
    }
    #pragma unroll
    for (int mi = 0; mi < 2; ++mi)
      #pragma unroll
      for (int ni = 0; ni < 4; ++ni)
        #pragma unroll
        for (int r = 0; r < 4; ++r){
          int o = h * 32 + mi * 16 + lg * 4 + r;
          int c = ni * 16 + l15;
          *(u16*)(wlj + o * 128 + ((2 * c) ^ ((o & 7) << 4))) = f2bf(fa[mi][ni][r]);
        }
  }
}

// ---------------- shared body: A-stage + split-fold + GEMM + BN partials [+ coop BN/apply] ----------------
template<int COOP>
__device__ __forceinline__ void fused_body(
    const u16* __restrict__ fb, const float* __restrict__ A,
    const float* __restrict__ WS, const float* __restrict__ WL3, const float* __restrict__ WL4,
    const u16* __restrict__ wat,
    const int* __restrict__ idxS, const int* __restrict__ idxL3, const int* __restrict__ idxL4,
    u16* __restrict__ H, float* __restrict__ bn_part, float* __restrict__ ss,
    const float* __restrict__ gamma, const float* __restrict__ beta, const float* __restrict__ pa,
    float* __restrict__ out)
{
  int bid = blockIdx.x;
  int n = (bid & 7) * 64 + (bid >> 3);              // XCD-chunked swizzle
  int tid = threadIdx.x, lane = tid & 63, wv = tid >> 6;
  int l15 = lane & 15, lg = lane >> 4;

  __shared__ u16 wl[5 * 4096];                      // 40,960 B : 5 W' slots (reused)
  __shared__ u16 albf[9 * 256 + 64];                //  4,736 B : a[j][b] bf16 (bnl aliases later)
  __shared__ int nbrl[12];

  if (tid < 9){
    int v;
    if (tid < 5) v = idxS[n * 5 + tid];
    else if (tid < 7) v = idxL3[n * 2 + (tid - 5)];
    else v = idxL4[n * 2 + (tid - 7)];
    nbrl[tid] = v;
  }

  // A-stage: one b per thread (9 values within 2 cache lines)
  if (tid < 256){
    int b = tid;
    const float* Ab = A + (size_t)b * (NN * NN) + (size_t)n * NN;
    #pragma unroll
    for (int j = 0; j < 9; ++j){
      int nb;
      if (j < 5) nb = idxS[n * 5 + j];
      else if (j < 7) nb = idxL3[n * 2 + (j - 5)];
      else nb = idxL4[n * 2 + (j - 7)];
      albf[j * 256 + b] = f2bf(Ab[nb]);
    }
  }

  // fold half 1: waves 0-4 fold hops 0-4 into slots 0-4
  if (wv < 5) fold_one(n, wv, (char*)wl + wv * 8192, wat, WS, WL3, WL4, l15, lg);
  __syncthreads();

  int rb = wv * 32;
  const size_t XROW = (size_t)NN * 64;
  const u16* xb0 = fb + (size_t)(rb + l15) * XROW + lg * 8;
  const u16* xb1 = xb0 + (size_t)16 * XROW;

  f32x4 acc[2][4];
  #pragma unroll
  for (int mi = 0; mi < 2; ++mi)
    #pragma unroll
    for (int ni = 0; ni < 4; ++ni){ acc[mi][ni][0]=0.f; acc[mi][ni][1]=0.f; acc[mi][ni][2]=0.f; acc[mi][ni][3]=0.f; }
  f32x4 kz; kz[0]=0.f; kz[1]=0.f; kz[2]=0.f; kz[3]=0.f;

  #pragma unroll 1
  for (int half = 0; half < 2; ++half){
    int j0 = half * 5, j1 = half * 5 + (half ? 4 : 5);
    #pragma unroll 1
    for (int j = j0; j < j1; ++j){
      int nbrj = nbrl[j];
      const char* wlj = (const char*)wl + (j - j0) * 8192;

      f32x4 avc[2];
      #pragma unroll
      for (int mi = 0; mi < 2; ++mi){
        u16x4 a4 = *(const u16x4*)(albf + j * 256 + rb + mi * 16 + lg * 4);
        avc[mi][0] = bf2f((u16)a4[0]); avc[mi][1] = bf2f((u16)a4[1]);
        avc[mi][2] = bf2f((u16)a4[2]); avc[mi][3] = bf2f((u16)a4[3]);
      }
      bf16x8 ax[2][2];
      ax[0][0] = *(const bf16x8*)(xb0 + nbrj * 64);
      ax[0][1] = *(const bf16x8*)(xb0 + nbrj * 64 + 32);
      ax[1][0] = *(const bf16x8*)(xb1 + nbrj * 64);
      ax[1][1] = *(const bf16x8*)(xb1 + nbrj * 64 + 32);
      bf16x8 bfr[2][4];
      #pragma unroll
      for (int ks = 0; ks < 2; ++ks)
        #pragma unroll
        for (int ni = 0; ni < 4; ++ni){
          int d = ni * 16 + l15;
          bfr[ks][ni] = *(const bf16x8*)(wlj + d * 128 + ((ks * 64 + lg * 16) ^ ((d & 7) << 4)));
        }

      #pragma unroll
      for (int mi = 0; mi < 2; ++mi){
        f32x4 P[4];
        #pragma unroll
        for (int ni = 0; ni < 4; ++ni){
          P[ni] = __builtin_amdgcn_mfma_f32_16x16x32_bf16(ax[mi][0], bfr[0][ni], kz, 0, 0, 0);
          P[ni] = __builtin_amdgcn_mfma_f32_16x16x32_bf16(ax[mi][1], bfr[1][ni], P[ni], 0, 0, 0);
        }
        #pragma unroll
        for (int ni = 0; ni < 4; ++ni){
          acc[mi][ni][0] += avc[mi][0] * P[ni][0];
          acc[mi][ni][1] += avc[mi][1] * P[ni][1];
          acc[mi][ni][2] += avc[mi][2] * P[ni][2];
          acc[mi][ni][3] += avc[mi][3] * P[ni][3];
        }
      }
    }
    if (half == 0){
      __syncthreads();                              // wl consumed
      if (wv < 4) fold_one(n, 5 + wv, (char*)wl + wv * 8192, wat, WS, WL3, WL4, l15, lg);
      __syncthreads();
    }
  }

  if (!COOP){
    // split path: H (pre-BN) as bf16
    #pragma unroll
    for (int mi = 0; mi < 2; ++mi)
      #pragma unroll
      for (int r = 0; r < 4; ++r){
        int bl = rb + mi * 16 + lg * 4 + r;
        u16* Hr = H + (size_t)bl * (NN * 64) + n * 64;
        #pragma unroll
        for (int ni = 0; ni < 4; ++ni)
          Hr[ni * 16 + l15] = f2bf(acc[mi][ni][r]);
      }
  }

  // BN partials (bnl aliases albf; all albf reads done)
  __syncthreads();
  float* bnl = (float*)albf;
  #pragma unroll
  for (int ni = 0; ni < 4; ++ni){
    float s = 0.f, sq = 0.f;
    #pragma unroll
    for (int mi = 0; mi < 2; ++mi)
      #pragma unroll
      for (int r = 0; r < 4; ++r){ float v = acc[mi][ni][r]; s += v; sq += v * v; }
    s  += __shfl_xor(s, 16);  s  += __shfl_xor(s, 32);
    sq += __shfl_xor(sq, 16); sq += __shfl_xor(sq, 32);
    if (lane < 16){
      bnl[wv * 128 + ni * 16 + lane]      = s;
      bnl[wv * 128 + 64 + ni * 16 + lane] = sq;
    }
  }
  __syncthreads();
  if (tid < 128){
    float s = 0.f;
    #pragma unroll
    for (int w = 0; w < 8; ++w) s += bnl[w * 128 + tid];
    bn_part[(size_t)bid * 128 + tid] = s;
  }
  __threadfence();

  if (COOP){
    cg::this_grid().sync();

    if (bid < 64){
      int d = bid;
      float s  = bn_part[(size_t)tid * 128 + d];
      float sq = bn_part[(size_t)tid * 128 + 64 + d];
      #pragma unroll
      for (int k = 1; k < 64; k <<= 1){
        s  += __shfl_xor(s, k);
        sq += __shfl_xor(sq, k);
      }
      float* red = (float*)wl;
      if (lane == 0){ red[wv] = s; red[8 + wv] = sq; }
      __syncthreads();
      if (tid == 0){
        float S = 0.f, SQ = 0.f;
        #pragma unroll
        for (int w = 0; w < 8; ++w){ S += red[w]; SQ += red[8 + w]; }
        float mean = S * (1.f / 131072.f);
        float var  = SQ * (1.f / 131072.f) - mean * mean;
        float sc = gamma[d] * rsqrtf(var + 1e-5f);
        ss[d] = sc;
        ss[64 + d] = beta[d] - mean * sc;
        __threadfence();
      }
    }

    cg::this_grid().sync();

    float aprelu = pa[0];
    float scv[4], shv[4];
    #pragma unroll
    for (int ni = 0; ni < 4; ++ni){
      int d = ni * 16 + l15;
      scv[ni] = ss[d];
      shv[ni] = ss[64 + d];
    }
    #pragma unroll
    for (int mi = 0; mi < 2; ++mi)
      #pragma unroll
      for (int r = 0; r < 4; ++r){
        int bl = rb + mi * 16 + lg * 4 + r;
        float* Or = out + (size_t)bl * (NN * 64) + n * 64;
        #pragma unroll
        for (int ni = 0; ni < 4; ++ni){
          float y = acc[mi][ni][r] * scv[ni] + shv[ni];
          Or[ni * 16 + l15] = y > 0.f ? y : aprelu * y;
        }
      }
  }
}

__global__ __launch_bounds__(512, 4) void k_fused_coop(
    const u16* fb, const float* A, const float* WS, const float* WL3, const float* WL4,
    const u16* wat, const int* idxS, const int* idxL3, const int* idxL4,
    u16* H, float* bn_part, float* ss, const float* gamma, const float* beta,
    const float* pa, float* out){
  fused_body<1>(fb, A, WS, WL3, WL4, wat, idxS, idxL3, idxL4, H, bn_part, ss, gamma, beta, pa, out);
}
__global__ __launch_bounds__(512, 4) void k_fused_split(
    const u16* fb, const float* A, const float* WS, const float* WL3, const float* WL4,
    const u16* wat, const int* idxS, const int* idxL3, const int* idxL4,
    u16* H, float* bn_part, float* ss, const float* gamma, const float* beta,
    const float* pa, float* out){
  fused_body<0>(fb, A, WS, WL3, WL4, wat, idxS, idxL3, idxL4, H, bn_part, ss, gamma, beta, pa, out);
}

// ---------------- fallback K: BN reduce ----------------
__global__ __launch_bounds__(1024) void k_reduce(const float* __restrict__ bn, const float* __restrict__ gamma,
    const float* __restrict__ beta, float* __restrict__ ss){
  __shared__ float red[2048];
  int t = threadIdx.x, d = t & 63, part = t >> 6;
  float s = 0.f, sq = 0.f;
  for (int w = part; w < 512; w += 16){
    s  += bn[w * 128 + d];
    sq += bn[w * 128 + 64 + d];
  }
  red[t] = s; red[1024 + t] = sq;
  __syncthreads();
  if (t < 64){
    float S = 0.f, SQ = 0.f;
    #pragma unroll
    for (int p = 0; p < 16; ++p){ S += red[p * 64 + t]; SQ += red[1024 + p * 64 + t]; }
    float mean = S * (1.f / 131072.f);
    float var  = SQ * (1.f / 131072.f) - mean * mean;
    float sc = gamma[t] * rsqrtf(var + 1e-5f);
    ss[t] = sc;
    ss[64 + t] = beta[t] - mean * sc;
  }
}

// ---------------- fallback K: BN + PReLU, bf16 H -> f32 out ----------------
__global__ __launch_bounds__(256) void k_apply(const u16* __restrict__ H, const float* __restrict__ ss,
    const float* __restrict__ pa, float* __restrict__ out){
  float a = pa[0];
  int i = blockIdx.x * 256 + threadIdx.x;
  uint4 v = ((const uint4*)H)[i];
  int d0 = (i << 3) & 63;
  float4 sc0 = *(const float4*)(ss + d0);
  float4 sc1 = *(const float4*)(ss + d0 + 4);
  float4 sh0 = *(const float4*)(ss + 64 + d0);
  float4 sh1 = *(const float4*)(ss + 68 + d0);
  float4 o0, o1; float y;
  y = bf2f((u16)(v.x & 0xffff)) * sc0.x + sh0.x; o0.x = y > 0.f ? y : a * y;
  y = bf2f((u16)(v.x >> 16))    * sc0.y + sh0.y; o0.y = y > 0.f ? y : a * y;
  y = bf2f((u16)(v.y & 0xffff)) * sc0.z + sh0.z; o0.z = y > 0.f ? y : a * y;
  y = bf2f((u16)(v.y >> 16))    * sc0.w + sh0.w; o0.w = y > 0.f ? y : a * y;
  y = bf2f((u16)(v.z & 0xffff)) * sc1.x + sh1.x; o1.x = y > 0.f ? y : a * y;
  y = bf2f((u16)(v.z >> 16))    * sc1.y + sh1.y; o1.y = y > 0.f ? y : a * y;
  y = bf2f((u16)(v.w & 0xffff)) * sc1.z + sh1.z; o1.z = y > 0.f ? y : a * y;
  y = bf2f((u16)(v.w >> 16))    * sc1.w + sh1.w; o1.w = y > 0.f ? y : a * y;
  ((float4*)out)[2 * i]     = o0;
  ((float4*)out)[2 * i + 1] = o1;
}

extern "C" void kernel_launch(void* const* d_in, const int* in_sizes, int n_in,
                              void* d_out, int out_size, void* d_ws, size_t ws_size,
                              hipStream_t stream){
  const float* f     = (const float*)d_in[0];
  const float* A     = (const float*)d_in[1];
  const float* WS    = (const float*)d_in[2];
  const float* WL3   = (const float*)d_in[3];
  const float* WL4   = (const float*)d_in[4];
  const float* Wa    = (const float*)d_in[5];
  const float* gamma = (const float*)d_in[6];
  const float* beta  = (const float*)d_in[7];
  const float* pa    = (const float*)d_in[8];
  const int* idxS    = (const int*)d_in[9];
  const int* idxL3   = (const int*)d_in[10];
  const int* idxL4   = (const int*)d_in[11];

  char* ws = (char*)d_ws;
  u16*   fbb = (u16*)(ws);                          // 16,777,216 B : features bf16
  u16*   Hb  = (u16*)(ws + 16777216);               // 16,777,216 B : H bf16 (fallback only)
  u16*   wat = (u16*)(ws + 33554432);               //     24,576 B : WaT bf16 padded
  float* bnp = (float*)(ws + 33579008);             //    262,144 B : BN partials [512][128]
  float* sss = (float*)(ws + 33841152);             //        512 B : scale/shift
  float* outp = (float*)d_out;

  k_prep<<<4144, 256, 0, stream>>>(f, fbb, Wa, wat);

  void* args[] = { (void*)&fbb, (void*)&A, (void*)&WS, (void*)&WL3, (void*)&WL4,
                   (void*)&wat, (void*)&idxS, (void*)&idxL3, (void*)&idxL4,
                   (void*)&Hb, (void*)&bnp, (void*)&sss, (void*)&gamma, (void*)&beta,
                   (void*)&pa, (void*)&outp };
  hipError_t e = hipLaunchCooperativeKernel((const void*)k_fused_coop, dim3(512), dim3(512),
                                            args, 0, stream);
  if (e != hipSuccess){
    k_fused_split<<<512, 512, 0, stream>>>(fbb, A, WS, WL3, WL4, wat, idxS, idxL3, idxL4,
                                           Hb, bnp, sss, gamma, beta, pa, outp);
    k_reduce<<<1,   1024, 0, stream>>>(bnp, gamma, beta, sss);
    k_apply <<<4096, 256, 0, stream>>>(Hb, sss, pa, outp);
  }
}

// Round 12
// 91.747 us; speedup vs baseline: 2.8737x; 2.8737x over previous
//
#include <hip/hip_runtime.h>
#include <hip/hip_bf16.h>

#define NN 512
#define BB 256

typedef unsigned short u16;
typedef unsigned int u32;
typedef __attribute__((ext_vector_type(8))) short bf16x8;
typedef __attribute__((ext_vector_type(4))) short u16x4;
typedef __attribute__((ext_vector_type(4))) float f32x4;
typedef __attribute__((ext_vector_type(4))) u32 u32x4;

__device__ __forceinline__ u16 f2bf(float x){
  u32 u = __builtin_bit_cast(u32, x);
  u32 r = u + 0x7fffu + ((u >> 16) & 1u);
  return (u16)(r >> 16);
}
__device__ __forceinline__ float bf2f(u16 h){
  return __builtin_bit_cast(float, (u32)h << 16);
}
__device__ __forceinline__ u32 cvtpk(float lo, float hi){
  float2 t; t.x = lo; t.y = hi;
  __hip_bfloat162 h = __float22bfloat162_rn(t);
  u32 r;
  __builtin_memcpy(&r, &h, 4);
  return r;
}
__device__ __forceinline__ bf16x8 pack8nc(float4 u, float4 v){
  u32x4 w;
  w[0] = cvtpk(u.x, u.y);
  w[1] = cvtpk(u.z, u.w);
  w[2] = cvtpk(v.x, v.y);
  w[3] = cvtpk(v.z, v.w);
  return __builtin_bit_cast(bf16x8, w);
}

// ---------------- K0: cast features f32->bf16  +  WaT build (fused) ----------------
__global__ __launch_bounds__(256) void k_prep(const float* __restrict__ f, u16* __restrict__ fb,
                                              const float* __restrict__ Wa, u16* __restrict__ wat){
  int b = blockIdx.x;
  if (b < 4096){
    int i = b * 256 + threadIdx.x;                  // 8 bf16 per thread
    const float4* p = (const float4*)f;
    float4 a = p[2*i], c = p[2*i+1];
    uint4 o;
    o.x = cvtpk(a.x, a.y); o.y = cvtpk(a.z, a.w);
    o.z = cvtpk(c.x, c.y); o.w = cvtpk(c.z, c.w);
    ((uint4*)fb)[i] = o;
  } else {
    int t = (b - 4096) * 256 + threadIdx.x;         // 64*192 = 12288 exact (48 blocks)
    int o = t / 192, r = t - o * 192;
    int blk = r >> 6, q = r & 63;
    float v = 0.f;
    if (blk == 0) v = Wa[q * 64 + o];
    else if (blk == 1) { if (q < 32) v = Wa[(64 + q) * 64 + o]; }
    else v = Wa[(96 + q) * 64 + o];
    wat[t] = f2bf(v);
  }
}

// ---------------- fold one hop's W' into a 8KB swizzled LDS slot ----------------
__device__ __forceinline__ void fold_one(int n, int jj, char* wlj, const u16* __restrict__ wat,
    const float* __restrict__ WS, const float* __restrict__ WL3, const float* __restrict__ WL4,
    int l15, int lg)
{
  const float* src; int jb, cstride;
  if (jj < 5)      { src = WS  + ((size_t)n * 5 + jj)       * 4096; jb = 0; cstride = 64; }
  else if (jj < 7) { src = WL3 + ((size_t)n * 2 + (jj - 5)) * 2048; jb = 1; cstride = 32; }
  else             { src = WL4 + ((size_t)n * 2 + (jj - 7)) * 4096; jb = 2; cstride = 64; }

  bf16x8 bw[4][2];
  #pragma unroll
  for (int ni = 0; ni < 4; ++ni){
    int c = ni * 16 + l15;
    const float* p = src + c * cstride + lg * 8;
    float4 u = *(const float4*)p, v = *(const float4*)(p + 4);
    bw[ni][0] = pack8nc(u, v);
    if (jb != 1){
      float4 u1 = *(const float4*)(p + 32), v1 = *(const float4*)(p + 36);
      bw[ni][1] = pack8nc(u1, v1);
    }
  }
  #pragma unroll
  for (int h = 0; h < 2; ++h){
    f32x4 fa[2][4];
    #pragma unroll
    for (int mi = 0; mi < 2; ++mi)
      #pragma unroll
      for (int ni = 0; ni < 4; ++ni){ fa[mi][ni][0]=0.f; fa[mi][ni][1]=0.f; fa[mi][ni][2]=0.f; fa[mi][ni][3]=0.f; }
    #pragma unroll
    for (int ks = 0; ks < 2; ++ks){
      if (jb == 1 && ks == 1) continue;             // upper mid-block zero for L3
      bf16x8 af0 = *(const bf16x8*)(wat + (h * 32 + l15) * 192      + jb * 64 + ks * 32 + lg * 8);
      bf16x8 af1 = *(const bf16x8*)(wat + (h * 32 + 16 + l15) * 192 + jb * 64 + ks * 32 + lg * 8);
      #pragma unroll
      for (int ni = 0; ni < 4; ++ni){
        fa[0][ni] = __builtin_amdgcn_mfma_f32_16x16x32_bf16(af0, bw[ni][ks], fa[0][ni], 0, 0, 0);
        fa[1][ni] = __builtin_amdgcn_mfma_f32_16x16x32_bf16(af1, bw[ni][ks], fa[1][ni], 0, 0, 0);
      }
    }
    #pragma unroll
    for (int mi = 0; mi < 2; ++mi)
      #pragma unroll
      for (int ni = 0; ni < 4; ++ni)
        #pragma unroll
        for (int r = 0; r < 4; ++r){
          int o = h * 32 + mi * 16 + lg * 4 + r;
          int c = ni * 16 + l15;
          *(u16*)(wlj + o * 128 + ((2 * c) ^ ((o & 7) << 4))) = f2bf(fa[mi][ni][r]);
        }
  }
}

// ---------------- K1: A-stage + split-fold + GEMM + H + BN partials ----------------
__global__ __launch_bounds__(512, 4) void k_main(
    const u16* __restrict__ fb, const float* __restrict__ A,
    const float* __restrict__ WS, const float* __restrict__ WL3, const float* __restrict__ WL4,
    const u16* __restrict__ wat,
    const int* __restrict__ idxS, const int* __restrict__ idxL3, const int* __restrict__ idxL4,
    u16* __restrict__ H, float* __restrict__ bn_part)
{
  int bid = blockIdx.x;
  int n = (bid & 7) * 64 + (bid >> 3);              // XCD-chunked swizzle
  int tid = threadIdx.x, lane = tid & 63, wv = tid >> 6;
  int l15 = lane & 15, lg = lane >> 4;

  __shared__ u16 wl[5 * 4096];                      // 40,960 B : 5 W' slots (reused across halves)
  __shared__ u16 albf[9 * 256 + 64];                //  4,736 B : a[j][b] bf16 (bnl aliases later)
  __shared__ int nbrl[12];

  if (tid < 9){
    int v;
    if (tid < 5) v = idxS[n * 5 + tid];
    else if (tid < 7) v = idxL3[n * 2 + (tid - 5)];
    else v = idxL4[n * 2 + (tid - 7)];
    nbrl[tid] = v;
  }

  // ---- A-stage on waves 5-7 (concurrent with fold half-1 on waves 0-4) ----
  if (wv >= 5){
    int i = tid - 320;                              // 0..191
    #pragma unroll
    for (int rep = 0; rep < 2; ++rep){
      int b = (rep == 0) ? i : i + 192;
      if (rep == 1 && i >= 64) break;
      const float* Ab = A + (size_t)b * (NN * NN) + (size_t)n * NN;
      #pragma unroll
      for (int j = 0; j < 9; ++j){
        int nb;
        if (j < 5) nb = idxS[n * 5 + j];
        else if (j < 7) nb = idxL3[n * 2 + (j - 5)];
        else nb = idxL4[n * 2 + (j - 7)];
        albf[j * 256 + b] = f2bf(Ab[nb]);
      }
    }
  }

  // ---- fold half 1: waves 0-4 fold hops 0-4 into slots 0-4 ----
  if (wv < 5) fold_one(n, wv, (char*)wl + wv * 8192, wat, WS, WL3, WL4, l15, lg);
  __syncthreads();

  int rb = wv * 32;
  const size_t XROW = (size_t)NN * 64;
  const u16* xb0 = fb + (size_t)(rb + l15) * XROW + lg * 8;
  const u16* xb1 = xb0 + (size_t)16 * XROW;

  f32x4 acc[2][4];
  #pragma unroll
  for (int mi = 0; mi < 2; ++mi)
    #pragma unroll
    for (int ni = 0; ni < 4; ++ni){ acc[mi][ni][0]=0.f; acc[mi][ni][1]=0.f; acc[mi][ni][2]=0.f; acc[mi][ni][3]=0.f; }
  f32x4 kz; kz[0]=0.f; kz[1]=0.f; kz[2]=0.f; kz[3]=0.f;

  #pragma unroll 1
  for (int half = 0; half < 2; ++half){
    int j0 = half * 5, j1 = half * 5 + (half ? 4 : 5);
    #pragma unroll 1
    for (int j = j0; j < j1; ++j){
      int nbrj = nbrl[j];
      const char* wlj = (const char*)wl + (j - j0) * 8192;

      f32x4 avc[2];
      #pragma unroll
      for (int mi = 0; mi < 2; ++mi){
        u16x4 a4 = *(const u16x4*)(albf + j * 256 + rb + mi * 16 + lg * 4);
        avc[mi][0] = bf2f((u16)a4[0]); avc[mi][1] = bf2f((u16)a4[1]);
        avc[mi][2] = bf2f((u16)a4[2]); avc[mi][3] = bf2f((u16)a4[3]);
      }
      bf16x8 ax[2][2];
      ax[0][0] = *(const bf16x8*)(xb0 + nbrj * 64);
      ax[0][1] = *(const bf16x8*)(xb0 + nbrj * 64 + 32);
      ax[1][0] = *(const bf16x8*)(xb1 + nbrj * 64);
      ax[1][1] = *(const bf16x8*)(xb1 + nbrj * 64 + 32);
      bf16x8 bfr[2][4];
      #pragma unroll
      for (int ks = 0; ks < 2; ++ks)
        #pragma unroll
        for (int ni = 0; ni < 4; ++ni){
          int d = ni * 16 + l15;
          bfr[ks][ni] = *(const bf16x8*)(wlj + d * 128 + ((ks * 64 + lg * 16) ^ ((d & 7) << 4)));
        }

      #pragma unroll
      for (int mi = 0; mi < 2; ++mi){
        f32x4 P[4];
        #pragma unroll
        for (int ni = 0; ni < 4; ++ni){
          P[ni] = __builtin_amdgcn_mfma_f32_16x16x32_bf16(ax[mi][0], bfr[0][ni], kz, 0, 0, 0);
          P[ni] = __builtin_amdgcn_mfma_f32_16x16x32_bf16(ax[mi][1], bfr[1][ni], P[ni], 0, 0, 0);
        }
        #pragma unroll
        for (int ni = 0; ni < 4; ++ni){
          acc[mi][ni][0] += avc[mi][0] * P[ni][0];
          acc[mi][ni][1] += avc[mi][1] * P[ni][1];
          acc[mi][ni][2] += avc[mi][2] * P[ni][2];
          acc[mi][ni][3] += avc[mi][3] * P[ni][3];
        }
      }
    }
    if (half == 0){
      __syncthreads();                              // wl half-1 consumed
      if (wv >= 4) fold_one(n, wv + 1, (char*)wl + (wv - 4) * 8192, wat, WS, WL3, WL4, l15, lg);
      __syncthreads();
    }
  }

  // ---- H (pre-BN) as bf16 ----
  #pragma unroll
  for (int mi = 0; mi < 2; ++mi)
    #pragma unroll
    for (int r = 0; r < 4; ++r){
      int bl = rb + mi * 16 + lg * 4 + r;
      u16* Hr = H + (size_t)bl * (NN * 64) + n * 64;
      #pragma unroll
      for (int ni = 0; ni < 4; ++ni)
        Hr[ni * 16 + l15] = f2bf(acc[mi][ni][r]);
    }

  // ---- BN partials (bnl aliases albf; all albf reads done) ----
  __syncthreads();
  float* bnl = (float*)albf;
  #pragma unroll
  for (int ni = 0; ni < 4; ++ni){
    float s = 0.f, sq = 0.f;
    #pragma unroll
    for (int mi = 0; mi < 2; ++mi)
      #pragma unroll
      for (int r = 0; r < 4; ++r){ float v = acc[mi][ni][r]; s += v; sq += v * v; }
    s  += __shfl_xor(s, 16);  s  += __shfl_xor(s, 32);
    sq += __shfl_xor(sq, 16); sq += __shfl_xor(sq, 32);
    if (lane < 16){
      bnl[wv * 128 + ni * 16 + lane]      = s;
      bnl[wv * 128 + 64 + ni * 16 + lane] = sq;
    }
  }
  __syncthreads();
  if (tid < 128){
    float s = 0.f;
    #pragma unroll
    for (int w = 0; w < 8; ++w) s += bnl[w * 128 + tid];
    bn_part[(size_t)bid * 128 + tid] = s;
  }
}

// ---------------- K2: BN reduce -> per-channel scale/shift ----------------
__global__ __launch_bounds__(1024) void k_reduce(const float* __restrict__ bn, const float* __restrict__ gamma,
    const float* __restrict__ beta, float* __restrict__ ss){
  __shared__ float red[2048];
  int t = threadIdx.x, d = t & 63, part = t >> 6;
  float s = 0.f, sq = 0.f;
  for (int w = part; w < 512; w += 16){
    s  += bn[w * 128 + d];
    sq += bn[w * 128 + 64 + d];
  }
  red[t] = s; red[1024 + t] = sq;
  __syncthreads();
  if (t < 64){
    float S = 0.f, SQ = 0.f;
    #pragma unroll
    for (int p = 0; p < 16; ++p){ S += red[p * 64 + t]; SQ += red[1024 + p * 64 + t]; }
    float mean = S * (1.f / 131072.f);
    float var  = SQ * (1.f / 131072.f) - mean * mean;
    float sc = gamma[t] * rsqrtf(var + 1e-5f);
    ss[t] = sc;
    ss[64 + t] = beta[t] - mean * sc;
  }
}

// ---------------- K3: BN + PReLU, bf16 H -> f32 out ----------------
__global__ __launch_bounds__(256) void k_apply(const u16* __restrict__ H, const float* __restrict__ ss,
    const float* __restrict__ pa, float* __restrict__ out){
  float a = pa[0];
  int i = blockIdx.x * 256 + threadIdx.x;
  uint4 v = ((const uint4*)H)[i];
  int d0 = (i << 3) & 63;
  float4 sc0 = *(const float4*)(ss + d0);
  float4 sc1 = *(const float4*)(ss + d0 + 4);
  float4 sh0 = *(const float4*)(ss + 64 + d0);
  float4 sh1 = *(const float4*)(ss + 68 + d0);
  float4 o0, o1; float y;
  y = bf2f((u16)(v.x & 0xffff)) * sc0.x + sh0.x; o0.x = y > 0.f ? y : a * y;
  y = bf2f((u16)(v.x >> 16))    * sc0.y + sh0.y; o0.y = y > 0.f ? y : a * y;
  y = bf2f((u16)(v.y & 0xffff)) * sc0.z + sh0.z; o0.z = y > 0.f ? y : a * y;
  y = bf2f((u16)(v.y >> 16))    * sc0.w + sh0.w; o0.w = y > 0.f ? y : a * y;
  y = bf2f((u16)(v.z & 0xffff)) * sc1.x + sh1.x; o1.x = y > 0.f ? y : a * y;
  y = bf2f((u16)(v.z >> 16))    * sc1.y + sh1.y; o1.y = y > 0.f ? y : a * y;
  y = bf2f((u16)(v.w & 0xffff)) * sc1.z + sh1.z; o1.z = y > 0.f ? y : a * y;
  y = bf2f((u16)(v.w >> 16))    * sc1.w + sh1.w; o1.w = y > 0.f ? y : a * y;
  ((float4*)out)[2 * i]     = o0;
  ((float4*)out)[2 * i + 1] = o1;
}

extern "C" void kernel_launch(void* const* d_in, const int* in_sizes, int n_in,
                              void* d_out, int out_size, void* d_ws, size_t ws_size,
                              hipStream_t stream){
  const float* f     = (const float*)d_in[0];
  const float* A     = (const float*)d_in[1];
  const float* WS    = (const float*)d_in[2];
  const float* WL3   = (const float*)d_in[3];
  const float* WL4   = (const float*)d_in[4];
  const float* Wa    = (const float*)d_in[5];
  const float* gamma = (const float*)d_in[6];
  const float* beta  = (const float*)d_in[7];
  const float* pa    = (const float*)d_in[8];
  const int* idxS    = (const int*)d_in[9];
  const int* idxL3   = (const int*)d_in[10];
  const int* idxL4   = (const int*)d_in[11];

  char* ws = (char*)d_ws;
  u16*   fbb = (u16*)(ws);                          // 16,777,216 B : features bf16
  u16*   Hb  = (u16*)(ws + 16777216);               // 16,777,216 B : H bf16
  u16*   wat = (u16*)(ws + 33554432);               //     24,576 B : WaT bf16 padded
  float* bnp = (float*)(ws + 33579008);             //    262,144 B : BN partials [512][128]
  float* sss = (float*)(ws + 33841152);             //        512 B : scale/shift

  k_prep  <<<4144, 256, 0, stream>>>(f, fbb, Wa, wat);
  k_main  <<<512,  512, 0, stream>>>(fbb, A, WS, WL3, WL4, wat, idxS, idxL3, idxL4, Hb, bnp);
  k_reduce<<<1,   1024, 0, stream>>>(bnp, gamma, beta, sss);
  k_apply <<<4096, 256, 0, stream>>>(Hb, sss, pa, (float*)d_out);
}

// Round 13
// 66.989 us; speedup vs baseline: 3.9358x; 1.3696x over previous
//
#include <hip/hip_runtime.h>
#include <hip/hip_bf16.h>

#define NN 512
#define BB 256

typedef unsigned short u16;
typedef unsigned int u32;
typedef __attribute__((ext_vector_type(8))) short bf16x8;
typedef __attribute__((ext_vector_type(4))) short u16x4;
typedef __attribute__((ext_vector_type(4))) float f32x4;
typedef __attribute__((ext_vector_type(4))) u32 u32x4;

__device__ __forceinline__ u16 f2bf(float x){
  u32 u = __builtin_bit_cast(u32, x);
  u32 r = u + 0x7fffu + ((u >> 16) & 1u);
  return (u16)(r >> 16);
}
__device__ __forceinline__ float bf2f(u16 h){
  return __builtin_bit_cast(float, (u32)h << 16);
}
__device__ __forceinline__ u32 cvtpk(float lo, float hi){
  float2 t; t.x = lo; t.y = hi;
  __hip_bfloat162 h = __float22bfloat162_rn(t);
  u32 r;
  __builtin_memcpy(&r, &h, 4);
  return r;
}
__device__ __forceinline__ bf16x8 pack8nc(float4 u, float4 v){
  u32x4 w;
  w[0] = cvtpk(u.x, u.y);
  w[1] = cvtpk(u.z, u.w);
  w[2] = cvtpk(v.x, v.y);
  w[3] = cvtpk(v.z, v.w);
  return __builtin_bit_cast(bf16x8, w);
}

// ---------------- K0: cast features f32->bf16  +  WaT build (fused) ----------------
__global__ __launch_bounds__(256) void k_prep(const float* __restrict__ f, u16* __restrict__ fb,
                                              const float* __restrict__ Wa, u16* __restrict__ wat){
  int b = blockIdx.x;
  if (b < 4096){
    int i = b * 256 + threadIdx.x;                  // 8 bf16 per thread
    const float4* p = (const float4*)f;
    float4 a = p[2*i], c = p[2*i+1];
    uint4 o;
    o.x = cvtpk(a.x, a.y); o.y = cvtpk(a.z, a.w);
    o.z = cvtpk(c.x, c.y); o.w = cvtpk(c.z, c.w);
    ((uint4*)fb)[i] = o;
  } else {
    int t = (b - 4096) * 256 + threadIdx.x;         // 64*192 = 12288 exact (48 blocks)
    int o = t / 192, r = t - o * 192;
    int blk = r >> 6, q = r & 63;
    float v = 0.f;
    if (blk == 0) v = Wa[q * 64 + o];
    else if (blk == 1) { if (q < 32) v = Wa[(64 + q) * 64 + o]; }
    else v = Wa[(96 + q) * 64 + o];
    wat[t] = f2bf(v);
  }
}

// ---------------- K1: A-stage + fold + GEMM + H + BN partials (round-8 proven structure) ----------------
__global__ __launch_bounds__(512, 4) void k_main(
    const u16* __restrict__ fb, const float* __restrict__ A,
    const float* __restrict__ WS, const float* __restrict__ WL3, const float* __restrict__ WL4,
    const u16* __restrict__ wat,
    const int* __restrict__ idxS, const int* __restrict__ idxL3, const int* __restrict__ idxL4,
    u16* __restrict__ H, float* __restrict__ bn_part)
{
  int bid = blockIdx.x;
  int n = (bid & 7) * 64 + (bid >> 3);              // XCD-chunked swizzle (512 % 8 == 0)
  int tid = threadIdx.x, lane = tid & 63, wv = tid >> 6;
  int l15 = lane & 15, lg = lane >> 4;

  __shared__ u16 wl[9 * 4096];                      // 73,728 B : 9 x (64x64 bf16, 128B rows, XOR-swz)
  __shared__ u16 albf[9 * 256 + 64];                //  4,736 B : a[j][b] bf16 (bnl aliases later)
  __shared__ int nbrl[12];

  if (tid < 9){
    int v;
    if (tid < 5) v = idxS[n * 5 + tid];
    else if (tid < 7) v = idxL3[n * 2 + (tid - 5)];
    else v = idxL4[n * 2 + (tid - 7)];
    nbrl[tid] = v;
  }

  // ---- A-stage: waves 0-3, one b per thread (values within 1-2 cache lines) ----
  if (tid < 256){
    int b = tid;
    const float* Ab = A + (size_t)b * (NN * NN) + (size_t)n * NN;
    #pragma unroll
    for (int j = 0; j < 9; ++j){
      int nb;
      if (j < 5) nb = idxS[n * 5 + j];
      else if (j < 7) nb = idxL3[n * 2 + (j - 5)];
      else nb = idxL4[n * 2 + (j - 7)];
      albf[j * 256 + b] = f2bf(Ab[nb]);
    }
  }

  // ---- fold: wave wv folds hop wv; wave 7 also folds hop 8 ----
  for (int jj = wv; jj < 9; jj += (wv == 7 ? 1 : 16)){
    const float* src; int jb, cstride;
    if (jj < 5)      { src = WS  + ((size_t)n * 5 + jj)       * 4096; jb = 0; cstride = 64; }
    else if (jj < 7) { src = WL3 + ((size_t)n * 2 + (jj - 5)) * 2048; jb = 1; cstride = 32; }
    else             { src = WL4 + ((size_t)n * 2 + (jj - 7)) * 4096; jb = 2; cstride = 64; }
    char* wlj = (char*)wl + jj * 8192;

    bf16x8 bw[4][2];
    #pragma unroll
    for (int ni = 0; ni < 4; ++ni){
      int c = ni * 16 + l15;
      const float* p = src + c * cstride + lg * 8;
      float4 u = *(const float4*)p, v = *(const float4*)(p + 4);
      bw[ni][0] = pack8nc(u, v);
      if (jb != 1){
        float4 u1 = *(const float4*)(p + 32), v1 = *(const float4*)(p + 36);
        bw[ni][1] = pack8nc(u1, v1);
      }
    }
    #pragma unroll
    for (int h = 0; h < 2; ++h){
      f32x4 fa[2][4];
      #pragma unroll
      for (int mi = 0; mi < 2; ++mi)
        #pragma unroll
        for (int ni = 0; ni < 4; ++ni){ fa[mi][ni][0]=0.f; fa[mi][ni][1]=0.f; fa[mi][ni][2]=0.f; fa[mi][ni][3]=0.f; }
      #pragma unroll
      for (int ks = 0; ks < 2; ++ks){
        if (jb == 1 && ks == 1) continue;           // upper mid-block zero for L3
        bf16x8 af0 = *(const bf16x8*)(wat + (h * 32 + l15) * 192      + jb * 64 + ks * 32 + lg * 8);
        bf16x8 af1 = *(const bf16x8*)(wat + (h * 32 + 16 + l15) * 192 + jb * 64 + ks * 32 + lg * 8);
        #pragma unroll
        for (int ni = 0; ni < 4; ++ni){
          fa[0][ni] = __builtin_amdgcn_mfma_f32_16x16x32_bf16(af0, bw[ni][ks], fa[0][ni], 0, 0, 0);
          fa[1][ni] = __builtin_amdgcn_mfma_f32_16x16x32_bf16(af1, bw[ni][ks], fa[1][ni], 0, 0, 0);
        }
      }
      #pragma unroll
      for (int mi = 0; mi < 2; ++mi)
        #pragma unroll
        for (int ni = 0; ni < 4; ++ni)
          #pragma unroll
          for (int r = 0; r < 4; ++r){
            int o = h * 32 + mi * 16 + lg * 4 + r;
            int c = ni * 16 + l15;
            *(u16*)(wlj + o * 128 + ((2 * c) ^ ((o & 7) << 4))) = f2bf(fa[mi][ni][r]);
          }
    }
  }
  __syncthreads();

  // ---- phase 2: rolled, barrier-free, in-loop loads (proven no-spill at 64 VGPR) ----
  int rb = wv * 32;
  const size_t XROW = (size_t)NN * 64;
  const u16* xb0 = fb + (size_t)(rb + l15) * XROW + lg * 8;
  const u16* xb1 = xb0 + (size_t)16 * XROW;

  f32x4 acc[2][4];
  #pragma unroll
  for (int mi = 0; mi < 2; ++mi)
    #pragma unroll
    for (int ni = 0; ni < 4; ++ni){ acc[mi][ni][0]=0.f; acc[mi][ni][1]=0.f; acc[mi][ni][2]=0.f; acc[mi][ni][3]=0.f; }
  f32x4 kz; kz[0]=0.f; kz[1]=0.f; kz[2]=0.f; kz[3]=0.f;

  #pragma unroll 1
  for (int j = 0; j < 9; ++j){
    int nbrj = nbrl[j];
    const char* wlj = (const char*)wl + j * 8192;

    f32x4 avc[2];
    #pragma unroll
    for (int mi = 0; mi < 2; ++mi){
      u16x4 a4 = *(const u16x4*)(albf + j * 256 + rb + mi * 16 + lg * 4);
      avc[mi][0] = bf2f((u16)a4[0]); avc[mi][1] = bf2f((u16)a4[1]);
      avc[mi][2] = bf2f((u16)a4[2]); avc[mi][3] = bf2f((u16)a4[3]);
    }
    bf16x8 ax[2][2];
    ax[0][0] = *(const bf16x8*)(xb0 + nbrj * 64);
    ax[0][1] = *(const bf16x8*)(xb0 + nbrj * 64 + 32);
    ax[1][0] = *(const bf16x8*)(xb1 + nbrj * 64);
    ax[1][1] = *(const bf16x8*)(xb1 + nbrj * 64 + 32);
    bf16x8 bfr[2][4];
    #pragma unroll
    for (int ks = 0; ks < 2; ++ks)
      #pragma unroll
      for (int ni = 0; ni < 4; ++ni){
        int d = ni * 16 + l15;
        bfr[ks][ni] = *(const bf16x8*)(wlj + d * 128 + ((ks * 64 + lg * 16) ^ ((d & 7) << 4)));
      }

    #pragma unroll
    for (int mi = 0; mi < 2; ++mi){
      f32x4 P[4];
      #pragma unroll
      for (int ni = 0; ni < 4; ++ni){
        P[ni] = __builtin_amdgcn_mfma_f32_16x16x32_bf16(ax[mi][0], bfr[0][ni], kz, 0, 0, 0);
        P[ni] = __builtin_amdgcn_mfma_f32_16x16x32_bf16(ax[mi][1], bfr[1][ni], P[ni], 0, 0, 0);
      }
      #pragma unroll
      for (int ni = 0; ni < 4; ++ni){
        acc[mi][ni][0] += avc[mi][0] * P[ni][0];
        acc[mi][ni][1] += avc[mi][1] * P[ni][1];
        acc[mi][ni][2] += avc[mi][2] * P[ni][2];
        acc[mi][ni][3] += avc[mi][3] * P[ni][3];
      }
    }
  }

  // ---- H (pre-BN) as bf16 ----
  #pragma unroll
  for (int mi = 0; mi < 2; ++mi)
    #pragma unroll
    for (int r = 0; r < 4; ++r){
      int bl = rb + mi * 16 + lg * 4 + r;
      u16* Hr = H + (size_t)bl * (NN * 64) + n * 64;
      #pragma unroll
      for (int ni = 0; ni < 4; ++ni)
        Hr[ni * 16 + l15] = f2bf(acc[mi][ni][r]);
    }

  // ---- BN partials (bnl aliases albf; all albf reads done) ----
  __syncthreads();
  float* bnl = (float*)albf;
  #pragma unroll
  for (int ni = 0; ni < 4; ++ni){
    float s = 0.f, sq = 0.f;
    #pragma unroll
    for (int mi = 0; mi < 2; ++mi)
      #pragma unroll
      for (int r = 0; r < 4; ++r){ float v = acc[mi][ni][r]; s += v; sq += v * v; }
    s  += __shfl_xor(s, 16);  s  += __shfl_xor(s, 32);
    sq += __shfl_xor(sq, 16); sq += __shfl_xor(sq, 32);
    if (lane < 16){
      bnl[wv * 128 + ni * 16 + lane]      = s;
      bnl[wv * 128 + 64 + ni * 16 + lane] = sq;
    }
  }
  __syncthreads();
  if (tid < 128){
    float s = 0.f;
    #pragma unroll
    for (int w = 0; w < 8; ++w) s += bnl[w * 128 + tid];
    bn_part[(size_t)bid * 128 + tid] = s;
  }
}

// ---------------- K2: BN reduce, 64 blocks (one per channel) ----------------
__global__ __launch_bounds__(512) void k_reduce(const float* __restrict__ bn, const float* __restrict__ gamma,
    const float* __restrict__ beta, float* __restrict__ ss){
  int d = blockIdx.x;                               // 0..63
  int t = threadIdx.x, wv = t >> 6, lane = t & 63;
  float s  = bn[(size_t)t * 128 + d];
  float sq = bn[(size_t)t * 128 + 64 + d];
  #pragma unroll
  for (int k = 1; k < 64; k <<= 1){
    s  += __shfl_xor(s, k);
    sq += __shfl_xor(sq, k);
  }
  __shared__ float red[16];
  if (lane == 0){ red[wv] = s; red[8 + wv] = sq; }
  __syncthreads();
  if (t == 0){
    float S = 0.f, SQ = 0.f;
    #pragma unroll
    for (int w = 0; w < 8; ++w){ S += red[w]; SQ += red[8 + w]; }
    float mean = S * (1.f / 131072.f);
    float var  = SQ * (1.f / 131072.f) - mean * mean;
    float sc = gamma[d] * rsqrtf(var + 1e-5f);
    ss[d] = sc;
    ss[64 + d] = beta[d] - mean * sc;
  }
}

// ---------------- K3: BN + PReLU, bf16 H -> f32 out ----------------
__global__ __launch_bounds__(256) void k_apply(const u16* __restrict__ H, const float* __restrict__ ss,
    const float* __restrict__ pa, float* __restrict__ out){
  float a = pa[0];
  int i = blockIdx.x * 256 + threadIdx.x;
  uint4 v = ((const uint4*)H)[i];
  int d0 = (i << 3) & 63;
  float4 sc0 = *(const float4*)(ss + d0);
  float4 sc1 = *(const float4*)(ss + d0 + 4);
  float4 sh0 = *(const float4*)(ss + 64 + d0);
  float4 sh1 = *(const float4*)(ss + 68 + d0);
  float4 o0, o1; float y;
  y = bf2f((u16)(v.x & 0xffff)) * sc0.x + sh0.x; o0.x = y > 0.f ? y : a * y;
  y = bf2f((u16)(v.x >> 16))    * sc0.y + sh0.y; o0.y = y > 0.f ? y : a * y;
  y = bf2f((u16)(v.y & 0xffff)) * sc0.z + sh0.z; o0.z = y > 0.f ? y : a * y;
  y = bf2f((u16)(v.y >> 16))    * sc0.w + sh0.w; o0.w = y > 0.f ? y : a * y;
  y = bf2f((u16)(v.z & 0xffff)) * sc1.x + sh1.x; o1.x = y > 0.f ? y : a * y;
  y = bf2f((u16)(v.z >> 16))    * sc1.y + sh1.y; o1.y = y > 0.f ? y : a * y;
  y = bf2f((u16)(v.w & 0xffff)) * sc1.z + sh1.z; o1.z = y > 0.f ? y : a * y;
  y = bf2f((u16)(v.w >> 16))    * sc1.w + sh1.w; o1.w = y > 0.f ? y : a * y;
  ((float4*)out)[2 * i]     = o0;
  ((float4*)out)[2 * i + 1] = o1;
}

extern "C" void kernel_launch(void* const* d_in, const int* in_sizes, int n_in,
                              void* d_out, int out_size, void* d_ws, size_t ws_size,
                              hipStream_t stream){
  const float* f     = (const float*)d_in[0];
  const float* A     = (const float*)d_in[1];
  const float* WS    = (const float*)d_in[2];
  const float* WL3   = (const float*)d_in[3];
  const float* WL4   = (const float*)d_in[4];
  const float* Wa    = (const float*)d_in[5];
  const float* gamma = (const float*)d_in[6];
  const float* beta  = (const float*)d_in[7];
  const float* pa    = (const float*)d_in[8];
  const int* idxS    = (const int*)d_in[9];
  const int* idxL3   = (const int*)d_in[10];
  const int* idxL4   = (const int*)d_in[11];

  char* ws = (char*)d_ws;
  u16*   fbb = (u16*)(ws);                          // 16,777,216 B : features bf16
  u16*   Hb  = (u16*)(ws + 16777216);               // 16,777,216 B : H bf16
  u16*   wat = (u16*)(ws + 33554432);               //     24,576 B : WaT bf16 padded
  float* bnp = (float*)(ws + 33579008);             //    262,144 B : BN partials [512][128]
  float* sss = (float*)(ws + 33841152);             //        512 B : scale/shift

  k_prep  <<<4144, 256, 0, stream>>>(f, fbb, Wa, wat);
  k_main  <<<512,  512, 0, stream>>>(fbb, A, WS, WL3, WL4, wat, idxS, idxL3, idxL4, Hb, bnp);
  k_reduce<<<64,   512, 0, stream>>>(bnp, gamma, beta, sss);
  k_apply <<<4096, 256, 0, stream>>>(Hb, sss, pa, (float*)d_out);
}